// Round 13
// baseline (726.367 us; speedup 1.0000x reference)
//
#include <hip/hip_runtime.h>
#include <hip/hip_fp16.h>
#include <math.h>

// ---------------------------------------------------------------------------
// DevignLite: 3-layer GCN + mean/max pool + MLP head.  N=100000, E=1.6M,
// D=64, G=256.
// Round 29: resubmit of r28 (GPUAcquisitionTimeout, never measured).
// Fuse pooling into L2 aggregate via atomics.  r27 post-mortem: persistent
// pipeline moved fp8 aggs 42.7->~34 (real win); fp16 L2 agg invariant at
// 44.3.  Line-rate math (fp16 77 G-lines/s > fp8 50) kills the line-rate
// theory; both sit at ~50 concurrent-misses/CU x ~250ns L3 = MSHR wall.
// Aggregate parked (5 theories tested).  This round removes work: L2 agg
// epilogue atomically accumulates hsum/hmax (64 f32 adds + 64 int maxes
// per node, values>=0 so int-max exact); cntg folded into k_bplace; k_pool
// DELETED along with its 12.8MB read and the L2 agg's 12.5MB y-write.
// (r14's failed pool-fusion was the serial-scan variant; this one adds no
// loop-carried work.)
// Predict: total 304.6 -> ~288-294; L2 agg 44.3 -> 45-47, WRITE_SIZE
// 12.5MB -> ~0.2MB; absmax ~1.9e-9 unchanged.  Revert if L2 agg +>10us.
// Ledger: r12=372; r15=366; r17=333.5; r21=332.3; r23=345.1 (split REV);
// r24 fp8 FAIL; r26=321.4 (mixed fp8); r27=304.6 (persistent agg: fp8 aggs
// ~34 each, fp16 44.3, absmax 1.86e-9); r28 infra-fail.
// ---------------------------------------------------------------------------

#define BKT_LOG 9
#define BKT (1 << BKT_LOG)
#define CHUNK 4096

typedef _Float16 h2 __attribute__((ext_vector_type(2)));
typedef _Float16 f16x4 __attribute__((ext_vector_type(4)));
typedef _Float16 f16x8 __attribute__((ext_vector_type(8)));
typedef float f32x2 __attribute__((ext_vector_type(2)));
typedef float f32x4 __attribute__((ext_vector_type(4)));

union HU { unsigned u; h2 h; };
__device__ inline h2 h2bits(unsigned u) { HU x; x.u = u; return x.h; }

#if __has_builtin(__builtin_amdgcn_fdot2)
#define FDOT2(a, b, c) __builtin_amdgcn_fdot2((a), (b), (c), false)
#else
__device__ inline float FDOT2(h2 a, h2 b, float c) {
  return (float)a.x * (float)b.x + (float)a.y * (float)b.y + c;
}
#endif

#define MASK_X 0x00003C00u   // half2 (1,0)
#define MASK_Y 0x3C000000u   // half2 (0,1)

// acc 4 floats += the 4 halfs packed in v (via fdot2 unit masks)
__device__ inline void acc4c(uint2 v, float& a0, float& a1, float& a2, float& a3) {
  h2 lo = h2bits(v.x), hi = h2bits(v.y);
  a0 = FDOT2(lo, h2bits(MASK_X), a0);
  a1 = FDOT2(lo, h2bits(MASK_Y), a1);
  a2 = FDOT2(hi, h2bits(MASK_X), a2);
  a3 = FDOT2(hi, h2bits(MASK_Y), a3);
}

#if __has_builtin(__builtin_amdgcn_cvt_pk_f32_fp8) && __has_builtin(__builtin_amdgcn_cvt_pk_fp8_f32)
#define HW_FP8 1
#else
#define HW_FP8 0
#endif

// ---- software fp8 e4m3fn codecs (fallback only) ----
__device__ inline float fp8dec_sw(unsigned b) {
  unsigned s = (b >> 7) & 1, e = (b >> 3) & 15, m = b & 7;
  float v;
  if (e == 0) v = (float)m * 0.001953125f;                  // m * 2^-9
  else v = __uint_as_float(((e + 120u) << 23) | (m << 20)); // 1.m * 2^(e-7)
  return s ? -v : v;
}
__device__ inline unsigned fp8enc_sw(float f) {
  unsigned s = (__float_as_uint(f) >> 31) << 7;
  float a = fabsf(f);
  if (!(a < 448.f)) return s | 0x7E;            // clamp (and NaN -> max)
  if (a < 0.0009765625f) return s;              // < 2^-10 -> 0
  int e; float m = frexpf(a, &e);               // a = m*2^e, m in [0.5,1)
  int E = e + 6;                                // exp field for 1.x*2^(e-1)
  unsigned q;
  if (E <= 0) {                                 // subnormal: round a/2^-9
    q = (unsigned)lrintf(a * 512.f);
    if (q >= 8) return s | 0x08;                // rolls to min normal
    return s | q;
  }
  q = (unsigned)lrintf((m * 2.f - 1.f) * 8.f);  // 0..8
  if (q == 8) { q = 0; E++; if (E > 15) return s | 0x7E; }
  return s | ((unsigned)E << 3) | q;
}

// decode 4 packed fp8 -> add into 4 float accumulators
__device__ inline void acc4fp8(unsigned v, float& a0, float& a1, float& a2, float& a3) {
#if HW_FP8
  f32x2 lo = __builtin_amdgcn_cvt_pk_f32_fp8((int)v, false);
  f32x2 hi = __builtin_amdgcn_cvt_pk_f32_fp8((int)v, true);
  a0 += lo[0]; a1 += lo[1]; a2 += hi[0]; a3 += hi[1];
#else
  a0 += fp8dec_sw(v & 255u);
  a1 += fp8dec_sw((v >> 8) & 255u);
  a2 += fp8dec_sw((v >> 16) & 255u);
  a3 += fp8dec_sw((v >> 24) & 255u);
#endif
}

// pack 4 floats -> 4 fp8 bytes
__device__ inline unsigned pk4fp8(float f0, float f1, float f2, float f3) {
#if HW_FP8
  int t = __builtin_amdgcn_cvt_pk_fp8_f32(f0, f1, 0, false);
  return (unsigned)__builtin_amdgcn_cvt_pk_fp8_f32(f2, f3, t, true);
#else
  return fp8enc_sw(f0) | (fp8enc_sw(f1) << 8) | (fp8enc_sw(f2) << 16) | (fp8enc_sw(f3) << 24);
#endif
}

// one macro-round: 8 row loads for edges [my, my+8) of window [e0,e1)
template <bool F8>
__device__ inline void rows8(const unsigned char* __restrict__ xh, int my,
                             int e0, int e1, int f, int4 iA, int4 iB,
                             float& a0, float& a1, float& a2, float& a3) {
  if (F8) {
    unsigned v0 = 0, v1 = 0, v2 = 0, v3 = 0, v4 = 0, v5 = 0, v6 = 0, v7 = 0;
    if (my + 0 >= e0 && my + 0 < e1) v0 = *(const unsigned*)(xh + ((size_t)(unsigned)iA.x << 6) + f * 4);
    if (my + 1 >= e0 && my + 1 < e1) v1 = *(const unsigned*)(xh + ((size_t)(unsigned)iA.y << 6) + f * 4);
    if (my + 2 >= e0 && my + 2 < e1) v2 = *(const unsigned*)(xh + ((size_t)(unsigned)iA.z << 6) + f * 4);
    if (my + 3 >= e0 && my + 3 < e1) v3 = *(const unsigned*)(xh + ((size_t)(unsigned)iA.w << 6) + f * 4);
    if (my + 4 >= e0 && my + 4 < e1) v4 = *(const unsigned*)(xh + ((size_t)(unsigned)iB.x << 6) + f * 4);
    if (my + 5 >= e0 && my + 5 < e1) v5 = *(const unsigned*)(xh + ((size_t)(unsigned)iB.y << 6) + f * 4);
    if (my + 6 >= e0 && my + 6 < e1) v6 = *(const unsigned*)(xh + ((size_t)(unsigned)iB.z << 6) + f * 4);
    if (my + 7 >= e0 && my + 7 < e1) v7 = *(const unsigned*)(xh + ((size_t)(unsigned)iB.w << 6) + f * 4);
    acc4fp8(v0, a0, a1, a2, a3);
    acc4fp8(v1, a0, a1, a2, a3);
    acc4fp8(v2, a0, a1, a2, a3);
    acc4fp8(v3, a0, a1, a2, a3);
    acc4fp8(v4, a0, a1, a2, a3);
    acc4fp8(v5, a0, a1, a2, a3);
    acc4fp8(v6, a0, a1, a2, a3);
    acc4fp8(v7, a0, a1, a2, a3);
  } else {
    uint2 v0 = {0,0}, v1 = {0,0}, v2 = {0,0}, v3 = {0,0};
    uint2 v4 = {0,0}, v5 = {0,0}, v6 = {0,0}, v7 = {0,0};
    if (my + 0 >= e0 && my + 0 < e1) v0 = *(const uint2*)(xh + ((size_t)(unsigned)iA.x << 7) + f * 8);
    if (my + 1 >= e0 && my + 1 < e1) v1 = *(const uint2*)(xh + ((size_t)(unsigned)iA.y << 7) + f * 8);
    if (my + 2 >= e0 && my + 2 < e1) v2 = *(const uint2*)(xh + ((size_t)(unsigned)iA.z << 7) + f * 8);
    if (my + 3 >= e0 && my + 3 < e1) v3 = *(const uint2*)(xh + ((size_t)(unsigned)iA.w << 7) + f * 8);
    if (my + 4 >= e0 && my + 4 < e1) v4 = *(const uint2*)(xh + ((size_t)(unsigned)iB.x << 7) + f * 8);
    if (my + 5 >= e0 && my + 5 < e1) v5 = *(const uint2*)(xh + ((size_t)(unsigned)iB.y << 7) + f * 8);
    if (my + 6 >= e0 && my + 6 < e1) v6 = *(const uint2*)(xh + ((size_t)(unsigned)iB.z << 7) + f * 8);
    if (my + 7 >= e0 && my + 7 < e1) v7 = *(const uint2*)(xh + ((size_t)(unsigned)iB.w << 7) + f * 8);
    acc4c(v0, a0, a1, a2, a3);
    acc4c(v1, a0, a1, a2, a3);
    acc4c(v2, a0, a1, a2, a3);
    acc4c(v3, a0, a1, a2, a3);
    acc4c(v4, a0, a1, a2, a3);
    acc4c(v5, a0, a1, a2, a3);
    acc4c(v6, a0, a1, a2, a3);
    acc4c(v7, a0, a1, a2, a3);
  }
}

// W conversion to fp16 B-frag layout (blocks 0-2) + workspace zeroing
// (block 3: bucket cursors, block 4: hsum/hmax/cntg).  Launched first.
__global__ __launch_bounds__(256) void k_wcvt(const float* __restrict__ W0,
                                              const float* __restrict__ W1,
                                              const float* __restrict__ W2,
                                              _Float16* __restrict__ Wf,
                                              int* __restrict__ gcur,
                                              float* __restrict__ hz, int hzn) {
  if (blockIdx.x < 3) {
    const float* W = (blockIdx.x == 0) ? W0 : (blockIdx.x == 1) ? W1 : W2;
    _Float16* out = Wf + blockIdx.x * 4096;
    for (int i = threadIdx.x; i < 4096; i += 256) {
      int c = i >> 10, s = (i >> 9) & 1, l = (i >> 3) & 63, j = i & 7;
      int k = 32 * s + 8 * (l >> 4) + j;
      int ncol = 16 * c + (l & 15);
      out[i] = (_Float16)W[k * 64 + ncol];
    }
  } else if (blockIdx.x == 3) {
    gcur[threadIdx.x] = 0;
  } else {
    for (int i = threadIdx.x; i < hzn; i += 256) hz[i] = 0.f;
  }
}

// partition v2: per-chunk in-LDS bucket sort, then COALESCED run writes into
// per-bucket padded regions (bucket b owns ebuf[b*S .. b*S+S)).
__global__ __launch_bounds__(256) void k_part(const int* __restrict__ src,
                                              const int* __restrict__ dst,
                                              int* __restrict__ gcur,
                                              int* __restrict__ ebuf,
                                              int E, int S) {
  __shared__ int pk[CHUNK];              // packed (ldst<<17 | src)
  __shared__ unsigned short bk[CHUNK];   // bucket id per element
  __shared__ unsigned short sp[CHUNK];   // sorted pos -> source idx
  __shared__ int h[256], sc[256], base[256], cur[256];
  int tid = threadIdx.x;
  long c0 = (long)blockIdx.x * CHUNK;
  int m = (int)min((long)CHUNK, (long)E - c0);
  h[tid] = 0;
  __syncthreads();
  for (int i = tid; i < m; i += 256) {
    int s = src[c0 + i];
    int d = dst[c0 + i];
    int b = d >> BKT_LOG;
    pk[i] = ((d & (BKT - 1)) << 17) | s;
    bk[i] = (unsigned short)b;
    atomicAdd(&h[b], 1);
  }
  __syncthreads();
  int hv = h[tid];
  if (hv) base[tid] = atomicAdd(&gcur[tid], hv);
  sc[tid] = hv;
  __syncthreads();
  for (int d = 1; d < 256; d <<= 1) {
    int t = (tid >= d) ? sc[tid - d] : 0;
    __syncthreads();
    sc[tid] += t;
    __syncthreads();
  }
  cur[tid] = sc[tid] - hv;   // exclusive scan
  __syncthreads();
  for (int i = tid; i < m; i += 256) {
    int p = atomicAdd(&cur[bk[i]], 1);
    sp[p] = (unsigned short)i;
  }
  __syncthreads();
  for (int j = tid; j < m; j += 256) {
    // smallest b with sc[b] > j
    int lo = 0, hi = 255;
    while (lo < hi) { int mid = (lo + hi) >> 1; if (sc[mid] > j) hi = mid; else lo = mid + 1; }
    int b = lo;
    int rel = j - (sc[b] - h[b]);
    int gpos = base[b] + rel;
    if (gpos < S)   // overflow guard (never taken: S = mean+45sigma)
      ebuf[(size_t)b * S + gpos] = pk[sp[j]];
  }
}

// per-bucket: node histogram (seeded with self-loop) + scan in LDS ->
// off/end/dinv, then place csrc (self first, then in-edges) within the
// bucket's padded region (single-writer).  deg includes self.
// Also folds the per-graph node count (cntg) histogram.
__global__ __launch_bounds__(512) void k_bplace(const int* __restrict__ ebuf,
                                                const int* __restrict__ gcur,
                                                const int* __restrict__ batch,
                                                int* __restrict__ off,
                                                int* __restrict__ eend,
                                                int* __restrict__ csrc,
                                                float* __restrict__ dinv,
                                                int* __restrict__ cntg,
                                                int N, int S) {
  __shared__ int s[512];
  __shared__ int cur[512];
  int b = blockIdx.x, tid = threadIdx.x;
  int n0 = b << BKT_LOG;
  int nn = min(BKT, N - n0);
  int e0 = b * S;
  int cnt = min(gcur[b], S - nn);   // reserve room for self-loops
  s[tid] = (tid < nn) ? 1 : 0;      // self-loop seed
  __syncthreads();
  for (int e = tid; e < cnt; e += 512) atomicAdd(&s[ebuf[e0 + e] >> 17], 1);
  __syncthreads();
  int degws = s[tid];               // 1 + in-degree (0 for phantom slots)
  for (int d = 1; d < 512; d <<= 1) {
    int t = (tid >= d) ? s[tid - d] : 0;
    __syncthreads();
    s[tid] += t;
    __syncthreads();
  }
  int excl = s[tid] - degws;
  if (tid < nn) {
    off[n0 + tid] = e0 + excl;
    eend[n0 + tid] = e0 + excl + degws;
    dinv[n0 + tid] = 1.0f / sqrtf((float)degws);
    csrc[e0 + excl] = n0 + tid;     // self first
    atomicAdd(&cntg[batch[n0 + tid]], 1);   // per-graph node count
  }
  cur[tid] = excl + ((tid < nn) ? 1 : 0);
  __syncthreads();
  for (int e = tid; e < cnt; e += 512) {
    int p = ebuf[e0 + e];
    int pos = e0 + atomicAdd(&cur[p >> 17], 1);
    csrc[pos] = p & 0x1FFFF;
  }
}

// ---------------------------------------------------------------------------
// MFMA matmul: xh[node] = enc( (in[node] @ W) * dinv[node]*scale )
// F8: xh rows 64B fp8 e4m3; else 128B fp16.
// EMB: in = fp32 emb rows gathered by tok; else fp16 y node-major.
// ---------------------------------------------------------------------------
template <bool EMB, bool F8>
__global__ __launch_bounds__(256) void k_mfmamm(const _Float16* __restrict__ y,
                                                const int* __restrict__ tok,
                                                const float* __restrict__ emb,
                                                const _Float16* __restrict__ Wf,
                                                const float* __restrict__ dinv,
                                                float scale,
                                                unsigned char* __restrict__ xh,
                                                int n) {
  __shared__ _Float16 lds[4 * 16 * 72];
  int w = threadIdx.x >> 6, l = threadIdx.x & 63;
  int m = l & 15, q = l >> 4;
  int rbase = blockIdx.x * 64 + w * 16;

  f16x8 a0, a1;
  if (EMB) {
    int node = min(rbase + m, n - 1);
    const float* er = emb + (size_t)tok[node] * 64;
    float4 v0 = *(const float4*)(er + q * 8);
    float4 v1 = *(const float4*)(er + q * 8 + 4);
    float4 v2 = *(const float4*)(er + 32 + q * 8);
    float4 v3 = *(const float4*)(er + 32 + q * 8 + 4);
    a0[0] = (_Float16)v0.x; a0[1] = (_Float16)v0.y; a0[2] = (_Float16)v0.z; a0[3] = (_Float16)v0.w;
    a0[4] = (_Float16)v1.x; a0[5] = (_Float16)v1.y; a0[6] = (_Float16)v1.z; a0[7] = (_Float16)v1.w;
    a1[0] = (_Float16)v2.x; a1[1] = (_Float16)v2.y; a1[2] = (_Float16)v2.z; a1[3] = (_Float16)v2.w;
    a1[4] = (_Float16)v3.x; a1[5] = (_Float16)v3.y; a1[6] = (_Float16)v3.z; a1[7] = (_Float16)v3.w;
  } else {
    int node = rbase + m;
    const _Float16* yr = y + ((size_t)(unsigned)node << 6);
    a0 = *(const f16x8*)(yr + q * 8);
    a1 = *(const f16x8*)(yr + 32 + q * 8);
  }
  float4 d4 = *(const float4*)(dinv + rbase + q * 4);

  const f16x8* wf = (const f16x8*)Wf + l;
  f32x4 acc[4];
#pragma unroll
  for (int c = 0; c < 4; c++) {
    f32x4 z = {0.f, 0.f, 0.f, 0.f};
    z = __builtin_amdgcn_mfma_f32_16x16x32_f16(a0, wf[(c * 2 + 0) * 64], z, 0, 0, 0);
    z = __builtin_amdgcn_mfma_f32_16x16x32_f16(a1, wf[(c * 2 + 1) * 64], z, 0, 0, 0);
    acc[c] = z;
  }

  const float ds[4] = {d4.x * scale, d4.y * scale, d4.z * scale, d4.w * scale};
  _Float16* ldw = lds + w * 16 * 72;
#pragma unroll
  for (int c = 0; c < 4; c++)
#pragma unroll
    for (int r = 0; r < 4; r++)
      ldw[(q * 4 + r) * 72 + c * 16 + m] = (_Float16)(acc[c][r] * ds[r]);
  __syncthreads();

  int row2 = l & 15, c2 = l >> 4;
  int node = rbase + row2;
  if (node < n) {
    if (F8) {
      const _Float16* sp16 = ldw + row2 * 72 + c2 * 16;
      unsigned wds[4];
#pragma unroll
      for (int k = 0; k < 4; k++)
        wds[k] = pk4fp8((float)sp16[4 * k + 0], (float)sp16[4 * k + 1],
                        (float)sp16[4 * k + 2], (float)sp16[4 * k + 3]);
      uint4 ov; ov.x = wds[0]; ov.y = wds[1]; ov.z = wds[2]; ov.w = wds[3];
      *(uint4*)(xh + ((size_t)(unsigned)node << 6) + c2 * 16) = ov;
    } else {
      const uint4* s4 = (const uint4*)(ldw + row2 * 72 + c2 * 16);
      uint4 v0 = s4[0], v1 = s4[1];
      uint4* dst = (uint4*)(xh + ((size_t)(unsigned)node << 7) + c2 * 32);
      dst[0] = v0;
      dst[1] = v1;
    }
  }
}

// ---------------------------------------------------------------------------
// Aggregate v5: persistent waves, depth-2 cross-node pipeline.
// 2048 blocks x 4 waves = 8192 waves; wave w does nodes w, w+8192, ...
// POOL: instead of writing y, atomically fold relu'd node row into
// hsum (f32 add) / hmax (int max; values>=0 so int compare exact).
// lane = (p:2b edge-slot, f:4b feature-quad); 32 edges in flight.
// ---------------------------------------------------------------------------
template <bool F8, bool POOL>
__global__ __launch_bounds__(256) void k_aggregate(const int* __restrict__ off,
                                                   const int* __restrict__ eend,
                                                   const int* __restrict__ csrc,
                                                   const float* __restrict__ dinv,
                                                   const unsigned char* __restrict__ xh,
                                                   const float* __restrict__ bias,
                                                   float invs,
                                                   _Float16* __restrict__ outp,
                                                   const int* __restrict__ batch,
                                                   float* __restrict__ hsum,
                                                   float* __restrict__ hmax,
                                                   int n, int stride) {
  int lane = threadIdx.x & 63;
  int p = lane >> 4;        // edge-slot group
  int f = lane & 15;        // feature quad
  int t = __builtin_amdgcn_readfirstlane(blockIdx.x * 4 + (threadIdx.x >> 6));
  if (t >= n) return;

  // prologue: node t extents + first indexes; node t+stride extents
  int e0 = off[t], e1 = eend[t];
  int4 iA = {0, 0, 0, 0}, iB = {0, 0, 0, 0};
  {
    int my = (e0 & ~7) + p * 8;
    if (my < e1) iA = *(const int4*)(csrc + my);
    if (my + 4 < e1) iB = *(const int4*)(csrc + my + 4);
  }
  int tn = t + stride;
  int e0n = 0, e1n = 0;
  if (tn < n) { e0n = off[tn]; e1n = eend[tn]; }

  while (true) {
    // (1) prefetch next node's first index vectors (e0n/e1n resident)
    int4 iAn = {0, 0, 0, 0}, iBn = {0, 0, 0, 0};
    if (tn < n) {
      int myn = (e0n & ~7) + p * 8;
      if (myn < e1n) iAn = *(const int4*)(csrc + myn);
      if (myn + 4 < e1n) iBn = *(const int4*)(csrc + myn + 4);
    }
    // (2) prefetch node t+2*stride extents (scalar)
    int tnn = tn + stride;
    int e0nn = 0, e1nn = 0;
    if (tnn < n) { e0nn = off[tnn]; e1nn = eend[tnn]; }

    // (3) body for node t
    float a0 = 0.f, a1 = 0.f, a2 = 0.f, a3 = 0.f;
    int base0 = e0 & ~7;
    rows8<F8>(xh, base0 + p * 8, e0, e1, f, iA, iB, a0, a1, a2, a3);
    for (int base = base0 + 32; base < e1; base += 32) {
      int my = base + p * 8;
      int4 jA = {0, 0, 0, 0}, jB = {0, 0, 0, 0};
      if (my < e1) jA = *(const int4*)(csrc + my);
      if (my + 4 < e1) jB = *(const int4*)(csrc + my + 4);
      rows8<F8>(xh, my, e0, e1, f, jA, jB, a0, a1, a2, a3);
    }

    // (4) reduce across the 4 p-groups (lane bits 4-5) + epilogue
    a0 += __shfl_xor(a0, 16); a0 += __shfl_xor(a0, 32);
    a1 += __shfl_xor(a1, 16); a1 += __shfl_xor(a1, 32);
    a2 += __shfl_xor(a2, 16); a2 += __shfl_xor(a2, 32);
    a3 += __shfl_xor(a3, 16); a3 += __shfl_xor(a3, 32);
    if (p == 0) {
      float sc = dinv[t] * invs;
      float4 bb = *(const float4*)(bias + f * 4);
      float v0 = fmaxf(a0 * sc + bb.x, 0.f) * 4096.f;
      float v1 = fmaxf(a1 * sc + bb.y, 0.f) * 4096.f;
      float v2 = fmaxf(a2 * sc + bb.z, 0.f) * 4096.f;
      float v3 = fmaxf(a3 * sc + bb.w, 0.f) * 4096.f;
      if (POOL) {
        int g = batch[t];
        float* hs = hsum + g * 64 + f * 4;
        int* hm = (int*)(hmax + g * 64 + f * 4);
        atomicAdd(hs + 0, v0);
        atomicAdd(hs + 1, v1);
        atomicAdd(hs + 2, v2);
        atomicAdd(hs + 3, v3);
        atomicMax(hm + 0, __float_as_int(v0));
        atomicMax(hm + 1, __float_as_int(v1));
        atomicMax(hm + 2, __float_as_int(v2));
        atomicMax(hm + 3, __float_as_int(v3));
      } else {
        f16x4 hv;
        hv[0] = (_Float16)v0;
        hv[1] = (_Float16)v1;
        hv[2] = (_Float16)v2;
        hv[3] = (_Float16)v3;
        *(f16x4*)((char*)outp + ((size_t)(unsigned)t << 7) + f * 8) = hv;
      }
    }

    // (5) rotate pipeline state
    if (tn >= n) break;
    t = tn; e0 = e0n; e1 = e1n; iA = iAn; iB = iBn;
    tn = tnn; e0n = e0nn; e1n = e1nn;
  }
}

// one block (64 threads) per graph: logits = relu(h@Wc1+bc1)@Wc2+bc2
// hsum/hmax carry the 4096x scale; undone here.
__global__ __launch_bounds__(64) void k_cls(const float* __restrict__ hsum,
                                            const float* __restrict__ hmax,
                                            const int* __restrict__ cnt,
                                            const float* __restrict__ Wc1,
                                            const float* __restrict__ bc1,
                                            const float* __restrict__ Wc2,
                                            const float* __restrict__ bc2,
                                            float* __restrict__ out) {
  __shared__ float h[128];
  __shared__ float hid[64];
  int g = blockIdx.x, j = threadIdx.x;
  int c = cnt[g];
  float cf = (float)(c > 0 ? c : 1);
  h[j] = hsum[g * 64 + j] / cf * (1.0f / 4096.0f);
  h[64 + j] = hmax[g * 64 + j] * (1.0f / 4096.0f);
  __syncthreads();
  float acc = bc1[j];
  for (int k = 0; k < 128; k++) acc += h[k] * Wc1[k * 64 + j];
  hid[j] = fmaxf(acc, 0.f);
  __syncthreads();
  if (j < 2) {
    float a = bc2[j];
    for (int k = 0; k < 64; k++) a += hid[k] * Wc2[k * 2 + j];
    out[g * 2 + j] = a;
  }
}

extern "C" void kernel_launch(void* const* d_in, const int* in_sizes, int n_in,
                              void* d_out, int out_size, void* d_ws, size_t ws_size,
                              hipStream_t stream) {
  const int N = in_sizes[0];
  const int E = in_sizes[1] / 2;
  const int G = out_size / 2;
  const int B = (N + BKT - 1) >> BKT_LOG;
  const int Npad = (N + 63) & ~63;
  // padded bucket stride: 1.5x mean occupancy + 256, rounded to 8 so that
  // bucket bases stay 8-int aligned (int4 index loads in k_aggregate)
  const int S = ((((E + B - 1) / B) * 3 / 2 + 256) + 7) & ~7;

  const int* tok   = (const int*)d_in[0];
  const int* ei    = (const int*)d_in[1];
  const int* batch = (const int*)d_in[2];
  const float* emb = (const float*)d_in[3];
  const float* W0 = (const float*)d_in[4];  const float* b0 = (const float*)d_in[5];
  const float* W1 = (const float*)d_in[6];  const float* b1 = (const float*)d_in[7];
  const float* W2 = (const float*)d_in[8];  const float* b2 = (const float*)d_in[9];
  const float* Wc1 = (const float*)d_in[10]; const float* bc1 = (const float*)d_in[11];
  const float* Wc2 = (const float*)d_in[12]; const float* bc2 = (const float*)d_in[13];
  const int* srcp = ei;
  const int* dstp = ei + E;

  // ---- workspace carve-up (4-byte units) ----
  int* off    = (int*)d_ws;                      // N
  int* eend   = off + N;                         // N
  float* dinv = (float*)(eend + N);              // Npad
  int* gcur   = (int*)(dinv + Npad);             // 256
  _Float16* Wf = (_Float16*)(gcur + 256);        // 3*4096 halfs (24 KB)
  int* csrc   = (int*)(Wf + 3 * 4096);           // B*S (padded, ~9.8 MB)
  unsigned char* xh = (unsigned char*)(csrc + (size_t)B * S);  // Npad rows:
                                                 // fp8 64B (L0/L1) or fp16 128B (L2)
  _Float16* y  = (_Float16*)(xh + (size_t)Npad * 128);  // Npad x 64 fp16
  int* ebuf   = (int*)y;                         // B*S ints, aliases y (dead
                                                 // before first aggregate)
  float* hsum = (float*)(y + (size_t)Npad * 64); // G*64
  float* hmax = hsum + (size_t)G * 64;           // G*64
  int*   cntg = (int*)(hmax + (size_t)G * 64);   // G

  auto cdiv = [](long a, long b) { return (int)((a + b - 1) / b); };
  const int aggBlocks = 2048;                    // persistent: 8192 waves
  const int aggStride = aggBlocks * 4;

  // ---- weight conversion + workspace zeroing ----
  k_wcvt<<<5, 256, 0, stream>>>(W0, W1, W2, Wf, gcur, hsum, G * 129);

  // ---- CSR build (padded buckets; self-loops folded in; cntg hist) ----
  k_part<<<cdiv(E, CHUNK), 256, 0, stream>>>(srcp, dstp, gcur, ebuf, E, S);
  k_bplace<<<B, 512, 0, stream>>>(ebuf, gcur, batch, off, eend, csrc, dinv, cntg, N, S);

  // ---- 3 GCN layers ----
  // L0 (fp8 rows): xh = fp8(emb@W0*dinv*256); agg invs=1/256.
  k_mfmamm<true, true><<<cdiv(N, 64), 256, 0, stream>>>(nullptr, tok, emb, Wf, dinv, 256.f, xh, N);
  k_aggregate<true, false><<<aggBlocks, 256, 0, stream>>>(off, eend, csrc, dinv, xh, b0, 1.f / 256.f, y, nullptr, nullptr, nullptr, N, aggStride);

  // L1 (fp8 rows): y carries x4096; scale=1.0 -> fp8 normals; invs=1/4096.
  k_mfmamm<false, true><<<cdiv(N, 64), 256, 0, stream>>>(y, nullptr, nullptr, Wf + 4096, dinv, 1.0f, xh, N);
  k_aggregate<true, false><<<aggBlocks, 256, 0, stream>>>(off, eend, csrc, dinv, xh, b1, 1.f / 4096.f, y, nullptr, nullptr, nullptr, N, aggStride);

  // L2 (fp16 rows, exact r21 numerics): scale=1/16, invs=1/256.
  // POOL epilogue: atomic hsum/hmax fold; no y write; k_pool deleted.
  k_mfmamm<false, false><<<cdiv(N, 64), 256, 0, stream>>>(y, nullptr, nullptr, Wf + 8192, dinv, 1.f / 16.f, xh, N);
  k_aggregate<false, true><<<aggBlocks, 256, 0, stream>>>(off, eend, csrc, dinv, xh, b2, 1.f / 256.f, nullptr, batch, hsum, hmax, N, aggStride);

  // ---- classifier head ----
  k_cls<<<G, 64, 0, stream>>>(hsum, hmax, cntg, Wc1, bc1, Wc2, bc2, (float*)d_out);
}

// Round 14
// 304.581 us; speedup vs baseline: 2.3848x; 2.3848x over previous
//
#include <hip/hip_runtime.h>
#include <hip/hip_fp16.h>
#include <math.h>

// ---------------------------------------------------------------------------
// DevignLite: 3-layer GCN + mean/max pool + MLP head.  N=100000, E=1.6M,
// D=64, G=256.
// Round 30: FULL REVERT to r27 (304.6us).  r29 pool-fusion post-mortem:
// L2 agg 44.3 -> ~380us.  WRITE_SIZE 12.5->200MB = 12.8M atomics x 16B:
// global atomics WRITE THROUGH to HBM on MI355X (don't coalesce in L2) and
// same-address serialization (390 nodes/graph x 128 cells) collapsed
// VALUBusy to 6.5%.  Pool fusion now falsified TWICE (r14 serial-scan,
// r29 atomic write-through) -> permanent dead list.  Rule: atomic fan-out
// must stay at segment-boundary counts (~400K, k_pool), never per-node x
// per-feature (12.8M).
// This round: exact r27 kernel, no piggybacked experiment (two failures in
// a row -> bank the best state; next change attributes vs 304.6).
// Predict: ~304-306us, absmax 1.86e-9, fp8 aggs ~34, fp16 agg ~44.
// Next levers: k_mfmamm<EMB> persistent-pipeline port (same wall class as
// aggregate), CSR-build dispatch-gap reduction.
// Ledger: r12=372; r15=366; r17=333.5; r21=332.3; r23=345.1 (split REV);
// r24 fp8 FAIL; r26=321.4; r27=304.6 (persistent agg); r29=726.4 (pool
// fusion REVERTED: atomic write-through).
// ---------------------------------------------------------------------------

#define BKT_LOG 9
#define BKT (1 << BKT_LOG)
#define CHUNK 4096

typedef _Float16 h2 __attribute__((ext_vector_type(2)));
typedef _Float16 f16x4 __attribute__((ext_vector_type(4)));
typedef _Float16 f16x8 __attribute__((ext_vector_type(8)));
typedef float f32x2 __attribute__((ext_vector_type(2)));
typedef float f32x4 __attribute__((ext_vector_type(4)));

union HU { unsigned u; h2 h; };
__device__ inline h2 h2bits(unsigned u) { HU x; x.u = u; return x.h; }

#if __has_builtin(__builtin_amdgcn_fdot2)
#define FDOT2(a, b, c) __builtin_amdgcn_fdot2((a), (b), (c), false)
#else
__device__ inline float FDOT2(h2 a, h2 b, float c) {
  return (float)a.x * (float)b.x + (float)a.y * (float)b.y + c;
}
#endif

#define MASK_X 0x00003C00u   // half2 (1,0)
#define MASK_Y 0x3C000000u   // half2 (0,1)

// acc 4 floats += the 4 halfs packed in v (via fdot2 unit masks)
__device__ inline void acc4c(uint2 v, float& a0, float& a1, float& a2, float& a3) {
  h2 lo = h2bits(v.x), hi = h2bits(v.y);
  a0 = FDOT2(lo, h2bits(MASK_X), a0);
  a1 = FDOT2(lo, h2bits(MASK_Y), a1);
  a2 = FDOT2(hi, h2bits(MASK_X), a2);
  a3 = FDOT2(hi, h2bits(MASK_Y), a3);
}

#if __has_builtin(__builtin_amdgcn_cvt_pk_f32_fp8) && __has_builtin(__builtin_amdgcn_cvt_pk_fp8_f32)
#define HW_FP8 1
#else
#define HW_FP8 0
#endif

// ---- software fp8 e4m3fn codecs (fallback only) ----
__device__ inline float fp8dec_sw(unsigned b) {
  unsigned s = (b >> 7) & 1, e = (b >> 3) & 15, m = b & 7;
  float v;
  if (e == 0) v = (float)m * 0.001953125f;                  // m * 2^-9
  else v = __uint_as_float(((e + 120u) << 23) | (m << 20)); // 1.m * 2^(e-7)
  return s ? -v : v;
}
__device__ inline unsigned fp8enc_sw(float f) {
  unsigned s = (__float_as_uint(f) >> 31) << 7;
  float a = fabsf(f);
  if (!(a < 448.f)) return s | 0x7E;            // clamp (and NaN -> max)
  if (a < 0.0009765625f) return s;              // < 2^-10 -> 0
  int e; float m = frexpf(a, &e);               // a = m*2^e, m in [0.5,1)
  int E = e + 6;                                // exp field for 1.x*2^(e-1)
  unsigned q;
  if (E <= 0) {                                 // subnormal: round a/2^-9
    q = (unsigned)lrintf(a * 512.f);
    if (q >= 8) return s | 0x08;                // rolls to min normal
    return s | q;
  }
  q = (unsigned)lrintf((m * 2.f - 1.f) * 8.f);  // 0..8
  if (q == 8) { q = 0; E++; if (E > 15) return s | 0x7E; }
  return s | ((unsigned)E << 3) | q;
}

// decode 4 packed fp8 -> add into 4 float accumulators
__device__ inline void acc4fp8(unsigned v, float& a0, float& a1, float& a2, float& a3) {
#if HW_FP8
  f32x2 lo = __builtin_amdgcn_cvt_pk_f32_fp8((int)v, false);
  f32x2 hi = __builtin_amdgcn_cvt_pk_f32_fp8((int)v, true);
  a0 += lo[0]; a1 += lo[1]; a2 += hi[0]; a3 += hi[1];
#else
  a0 += fp8dec_sw(v & 255u);
  a1 += fp8dec_sw((v >> 8) & 255u);
  a2 += fp8dec_sw((v >> 16) & 255u);
  a3 += fp8dec_sw((v >> 24) & 255u);
#endif
}

// pack 4 floats -> 4 fp8 bytes
__device__ inline unsigned pk4fp8(float f0, float f1, float f2, float f3) {
#if HW_FP8
  int t = __builtin_amdgcn_cvt_pk_fp8_f32(f0, f1, 0, false);
  return (unsigned)__builtin_amdgcn_cvt_pk_fp8_f32(f2, f3, t, true);
#else
  return fp8enc_sw(f0) | (fp8enc_sw(f1) << 8) | (fp8enc_sw(f2) << 16) | (fp8enc_sw(f3) << 24);
#endif
}

// one macro-round: 8 row loads for edges [my, my+8) of window [e0,e1)
template <bool F8>
__device__ inline void rows8(const unsigned char* __restrict__ xh, int my,
                             int e0, int e1, int f, int4 iA, int4 iB,
                             float& a0, float& a1, float& a2, float& a3) {
  if (F8) {
    unsigned v0 = 0, v1 = 0, v2 = 0, v3 = 0, v4 = 0, v5 = 0, v6 = 0, v7 = 0;
    if (my + 0 >= e0 && my + 0 < e1) v0 = *(const unsigned*)(xh + ((size_t)(unsigned)iA.x << 6) + f * 4);
    if (my + 1 >= e0 && my + 1 < e1) v1 = *(const unsigned*)(xh + ((size_t)(unsigned)iA.y << 6) + f * 4);
    if (my + 2 >= e0 && my + 2 < e1) v2 = *(const unsigned*)(xh + ((size_t)(unsigned)iA.z << 6) + f * 4);
    if (my + 3 >= e0 && my + 3 < e1) v3 = *(const unsigned*)(xh + ((size_t)(unsigned)iA.w << 6) + f * 4);
    if (my + 4 >= e0 && my + 4 < e1) v4 = *(const unsigned*)(xh + ((size_t)(unsigned)iB.x << 6) + f * 4);
    if (my + 5 >= e0 && my + 5 < e1) v5 = *(const unsigned*)(xh + ((size_t)(unsigned)iB.y << 6) + f * 4);
    if (my + 6 >= e0 && my + 6 < e1) v6 = *(const unsigned*)(xh + ((size_t)(unsigned)iB.z << 6) + f * 4);
    if (my + 7 >= e0 && my + 7 < e1) v7 = *(const unsigned*)(xh + ((size_t)(unsigned)iB.w << 6) + f * 4);
    acc4fp8(v0, a0, a1, a2, a3);
    acc4fp8(v1, a0, a1, a2, a3);
    acc4fp8(v2, a0, a1, a2, a3);
    acc4fp8(v3, a0, a1, a2, a3);
    acc4fp8(v4, a0, a1, a2, a3);
    acc4fp8(v5, a0, a1, a2, a3);
    acc4fp8(v6, a0, a1, a2, a3);
    acc4fp8(v7, a0, a1, a2, a3);
  } else {
    uint2 v0 = {0,0}, v1 = {0,0}, v2 = {0,0}, v3 = {0,0};
    uint2 v4 = {0,0}, v5 = {0,0}, v6 = {0,0}, v7 = {0,0};
    if (my + 0 >= e0 && my + 0 < e1) v0 = *(const uint2*)(xh + ((size_t)(unsigned)iA.x << 7) + f * 8);
    if (my + 1 >= e0 && my + 1 < e1) v1 = *(const uint2*)(xh + ((size_t)(unsigned)iA.y << 7) + f * 8);
    if (my + 2 >= e0 && my + 2 < e1) v2 = *(const uint2*)(xh + ((size_t)(unsigned)iA.z << 7) + f * 8);
    if (my + 3 >= e0 && my + 3 < e1) v3 = *(const uint2*)(xh + ((size_t)(unsigned)iA.w << 7) + f * 8);
    if (my + 4 >= e0 && my + 4 < e1) v4 = *(const uint2*)(xh + ((size_t)(unsigned)iB.x << 7) + f * 8);
    if (my + 5 >= e0 && my + 5 < e1) v5 = *(const uint2*)(xh + ((size_t)(unsigned)iB.y << 7) + f * 8);
    if (my + 6 >= e0 && my + 6 < e1) v6 = *(const uint2*)(xh + ((size_t)(unsigned)iB.z << 7) + f * 8);
    if (my + 7 >= e0 && my + 7 < e1) v7 = *(const uint2*)(xh + ((size_t)(unsigned)iB.w << 7) + f * 8);
    acc4c(v0, a0, a1, a2, a3);
    acc4c(v1, a0, a1, a2, a3);
    acc4c(v2, a0, a1, a2, a3);
    acc4c(v3, a0, a1, a2, a3);
    acc4c(v4, a0, a1, a2, a3);
    acc4c(v5, a0, a1, a2, a3);
    acc4c(v6, a0, a1, a2, a3);
    acc4c(v7, a0, a1, a2, a3);
  }
}

// W conversion to fp16 B-frag layout (blocks 0-2) + workspace zeroing
// (block 3: bucket cursors, block 4: hsum/hmax/cntg).  Launched first.
__global__ __launch_bounds__(256) void k_wcvt(const float* __restrict__ W0,
                                              const float* __restrict__ W1,
                                              const float* __restrict__ W2,
                                              _Float16* __restrict__ Wf,
                                              int* __restrict__ gcur,
                                              float* __restrict__ hz, int hzn) {
  if (blockIdx.x < 3) {
    const float* W = (blockIdx.x == 0) ? W0 : (blockIdx.x == 1) ? W1 : W2;
    _Float16* out = Wf + blockIdx.x * 4096;
    for (int i = threadIdx.x; i < 4096; i += 256) {
      int c = i >> 10, s = (i >> 9) & 1, l = (i >> 3) & 63, j = i & 7;
      int k = 32 * s + 8 * (l >> 4) + j;
      int ncol = 16 * c + (l & 15);
      out[i] = (_Float16)W[k * 64 + ncol];
    }
  } else if (blockIdx.x == 3) {
    gcur[threadIdx.x] = 0;
  } else {
    for (int i = threadIdx.x; i < hzn; i += 256) hz[i] = 0.f;
  }
}

// partition v2: per-chunk in-LDS bucket sort, then COALESCED run writes into
// per-bucket padded regions (bucket b owns ebuf[b*S .. b*S+S)).
__global__ __launch_bounds__(256) void k_part(const int* __restrict__ src,
                                              const int* __restrict__ dst,
                                              int* __restrict__ gcur,
                                              int* __restrict__ ebuf,
                                              int E, int S) {
  __shared__ int pk[CHUNK];              // packed (ldst<<17 | src)
  __shared__ unsigned short bk[CHUNK];   // bucket id per element
  __shared__ unsigned short sp[CHUNK];   // sorted pos -> source idx
  __shared__ int h[256], sc[256], base[256], cur[256];
  int tid = threadIdx.x;
  long c0 = (long)blockIdx.x * CHUNK;
  int m = (int)min((long)CHUNK, (long)E - c0);
  h[tid] = 0;
  __syncthreads();
  for (int i = tid; i < m; i += 256) {
    int s = src[c0 + i];
    int d = dst[c0 + i];
    int b = d >> BKT_LOG;
    pk[i] = ((d & (BKT - 1)) << 17) | s;
    bk[i] = (unsigned short)b;
    atomicAdd(&h[b], 1);
  }
  __syncthreads();
  int hv = h[tid];
  if (hv) base[tid] = atomicAdd(&gcur[tid], hv);
  sc[tid] = hv;
  __syncthreads();
  for (int d = 1; d < 256; d <<= 1) {
    int t = (tid >= d) ? sc[tid - d] : 0;
    __syncthreads();
    sc[tid] += t;
    __syncthreads();
  }
  cur[tid] = sc[tid] - hv;   // exclusive scan
  __syncthreads();
  for (int i = tid; i < m; i += 256) {
    int p = atomicAdd(&cur[bk[i]], 1);
    sp[p] = (unsigned short)i;
  }
  __syncthreads();
  for (int j = tid; j < m; j += 256) {
    // smallest b with sc[b] > j
    int lo = 0, hi = 255;
    while (lo < hi) { int mid = (lo + hi) >> 1; if (sc[mid] > j) hi = mid; else lo = mid + 1; }
    int b = lo;
    int rel = j - (sc[b] - h[b]);
    int gpos = base[b] + rel;
    if (gpos < S)   // overflow guard (never taken: S = mean+45sigma)
      ebuf[(size_t)b * S + gpos] = pk[sp[j]];
  }
}

// per-bucket: node histogram (seeded with self-loop) + scan in LDS ->
// off/end/dinv, then place csrc (self first, then in-edges) within the
// bucket's padded region (single-writer).  deg includes self.
__global__ __launch_bounds__(512) void k_bplace(const int* __restrict__ ebuf,
                                                const int* __restrict__ gcur,
                                                int* __restrict__ off,
                                                int* __restrict__ eend,
                                                int* __restrict__ csrc,
                                                float* __restrict__ dinv,
                                                int N, int S) {
  __shared__ int s[512];
  __shared__ int cur[512];
  int b = blockIdx.x, tid = threadIdx.x;
  int n0 = b << BKT_LOG;
  int nn = min(BKT, N - n0);
  int e0 = b * S;
  int cnt = min(gcur[b], S - nn);   // reserve room for self-loops
  s[tid] = (tid < nn) ? 1 : 0;      // self-loop seed
  __syncthreads();
  for (int e = tid; e < cnt; e += 512) atomicAdd(&s[ebuf[e0 + e] >> 17], 1);
  __syncthreads();
  int degws = s[tid];               // 1 + in-degree (0 for phantom slots)
  for (int d = 1; d < 512; d <<= 1) {
    int t = (tid >= d) ? s[tid - d] : 0;
    __syncthreads();
    s[tid] += t;
    __syncthreads();
  }
  int excl = s[tid] - degws;
  if (tid < nn) {
    off[n0 + tid] = e0 + excl;
    eend[n0 + tid] = e0 + excl + degws;
    dinv[n0 + tid] = 1.0f / sqrtf((float)degws);
    csrc[e0 + excl] = n0 + tid;     // self first
  }
  cur[tid] = excl + ((tid < nn) ? 1 : 0);
  __syncthreads();
  for (int e = tid; e < cnt; e += 512) {
    int p = ebuf[e0 + e];
    int pos = e0 + atomicAdd(&cur[p >> 17], 1);
    csrc[pos] = p & 0x1FFFF;
  }
}

// ---------------------------------------------------------------------------
// MFMA matmul: xh[node] = enc( (in[node] @ W) * dinv[node]*scale )
// F8: xh rows 64B fp8 e4m3; else 128B fp16.
// EMB: in = fp32 emb rows gathered by tok; else fp16 y node-major.
// ---------------------------------------------------------------------------
template <bool EMB, bool F8>
__global__ __launch_bounds__(256) void k_mfmamm(const _Float16* __restrict__ y,
                                                const int* __restrict__ tok,
                                                const float* __restrict__ emb,
                                                const _Float16* __restrict__ Wf,
                                                const float* __restrict__ dinv,
                                                float scale,
                                                unsigned char* __restrict__ xh,
                                                int n) {
  __shared__ _Float16 lds[4 * 16 * 72];
  int w = threadIdx.x >> 6, l = threadIdx.x & 63;
  int m = l & 15, q = l >> 4;
  int rbase = blockIdx.x * 64 + w * 16;

  f16x8 a0, a1;
  if (EMB) {
    int node = min(rbase + m, n - 1);
    const float* er = emb + (size_t)tok[node] * 64;
    float4 v0 = *(const float4*)(er + q * 8);
    float4 v1 = *(const float4*)(er + q * 8 + 4);
    float4 v2 = *(const float4*)(er + 32 + q * 8);
    float4 v3 = *(const float4*)(er + 32 + q * 8 + 4);
    a0[0] = (_Float16)v0.x; a0[1] = (_Float16)v0.y; a0[2] = (_Float16)v0.z; a0[3] = (_Float16)v0.w;
    a0[4] = (_Float16)v1.x; a0[5] = (_Float16)v1.y; a0[6] = (_Float16)v1.z; a0[7] = (_Float16)v1.w;
    a1[0] = (_Float16)v2.x; a1[1] = (_Float16)v2.y; a1[2] = (_Float16)v2.z; a1[3] = (_Float16)v2.w;
    a1[4] = (_Float16)v3.x; a1[5] = (_Float16)v3.y; a1[6] = (_Float16)v3.z; a1[7] = (_Float16)v3.w;
  } else {
    int node = rbase + m;
    const _Float16* yr = y + ((size_t)(unsigned)node << 6);
    a0 = *(const f16x8*)(yr + q * 8);
    a1 = *(const f16x8*)(yr + 32 + q * 8);
  }
  float4 d4 = *(const float4*)(dinv + rbase + q * 4);

  const f16x8* wf = (const f16x8*)Wf + l;
  f32x4 acc[4];
#pragma unroll
  for (int c = 0; c < 4; c++) {
    f32x4 z = {0.f, 0.f, 0.f, 0.f};
    z = __builtin_amdgcn_mfma_f32_16x16x32_f16(a0, wf[(c * 2 + 0) * 64], z, 0, 0, 0);
    z = __builtin_amdgcn_mfma_f32_16x16x32_f16(a1, wf[(c * 2 + 1) * 64], z, 0, 0, 0);
    acc[c] = z;
  }

  const float ds[4] = {d4.x * scale, d4.y * scale, d4.z * scale, d4.w * scale};
  _Float16* ldw = lds + w * 16 * 72;
#pragma unroll
  for (int c = 0; c < 4; c++)
#pragma unroll
    for (int r = 0; r < 4; r++)
      ldw[(q * 4 + r) * 72 + c * 16 + m] = (_Float16)(acc[c][r] * ds[r]);
  __syncthreads();

  int row2 = l & 15, c2 = l >> 4;
  int node = rbase + row2;
  if (node < n) {
    if (F8) {
      const _Float16* sp16 = ldw + row2 * 72 + c2 * 16;
      unsigned wds[4];
#pragma unroll
      for (int k = 0; k < 4; k++)
        wds[k] = pk4fp8((float)sp16[4 * k + 0], (float)sp16[4 * k + 1],
                        (float)sp16[4 * k + 2], (float)sp16[4 * k + 3]);
      uint4 ov; ov.x = wds[0]; ov.y = wds[1]; ov.z = wds[2]; ov.w = wds[3];
      *(uint4*)(xh + ((size_t)(unsigned)node << 6) + c2 * 16) = ov;
    } else {
      const uint4* s4 = (const uint4*)(ldw + row2 * 72 + c2 * 16);
      uint4 v0 = s4[0], v1 = s4[1];
      uint4* dst = (uint4*)(xh + ((size_t)(unsigned)node << 7) + c2 * 32);
      dst[0] = v0;
      dst[1] = v1;
    }
  }
}

// ---------------------------------------------------------------------------
// Aggregate v4: persistent waves, depth-2 cross-node pipeline.
// 2048 blocks x 4 waves = 8192 waves; wave w does nodes w, w+8192, ...
// Entering iteration for node t: e0/e1 + first index int4s (iA/iB) resident,
// next node's extents (e0n/e1n) resident.  Iteration issues next node's
// index prefetch + next-next extents BEFORE consuming t's rows.
// lane = (p:2b edge-slot, f:4b feature-quad); 32 edges in flight.
// out[t][64] = fp16 4096*relu(sum * dinv[t]*invs + bias).
// ---------------------------------------------------------------------------
template <bool F8>
__global__ __launch_bounds__(256) void k_aggregate(const int* __restrict__ off,
                                                   const int* __restrict__ eend,
                                                   const int* __restrict__ csrc,
                                                   const float* __restrict__ dinv,
                                                   const unsigned char* __restrict__ xh,
                                                   const float* __restrict__ bias,
                                                   float invs,
                                                   _Float16* __restrict__ outp,
                                                   int n, int stride) {
  int lane = threadIdx.x & 63;
  int p = lane >> 4;        // edge-slot group
  int f = lane & 15;        // feature quad
  int t = __builtin_amdgcn_readfirstlane(blockIdx.x * 4 + (threadIdx.x >> 6));
  if (t >= n) return;

  // prologue: node t extents + first indexes; node t+stride extents
  int e0 = off[t], e1 = eend[t];
  int4 iA = {0, 0, 0, 0}, iB = {0, 0, 0, 0};
  {
    int my = (e0 & ~7) + p * 8;
    if (my < e1) iA = *(const int4*)(csrc + my);
    if (my + 4 < e1) iB = *(const int4*)(csrc + my + 4);
  }
  int tn = t + stride;
  int e0n = 0, e1n = 0;
  if (tn < n) { e0n = off[tn]; e1n = eend[tn]; }

  while (true) {
    // (1) prefetch next node's first index vectors (e0n/e1n resident)
    int4 iAn = {0, 0, 0, 0}, iBn = {0, 0, 0, 0};
    if (tn < n) {
      int myn = (e0n & ~7) + p * 8;
      if (myn < e1n) iAn = *(const int4*)(csrc + myn);
      if (myn + 4 < e1n) iBn = *(const int4*)(csrc + myn + 4);
    }
    // (2) prefetch node t+2*stride extents (scalar)
    int tnn = tn + stride;
    int e0nn = 0, e1nn = 0;
    if (tnn < n) { e0nn = off[tnn]; e1nn = eend[tnn]; }

    // (3) body for node t
    float a0 = 0.f, a1 = 0.f, a2 = 0.f, a3 = 0.f;
    int base0 = e0 & ~7;
    rows8<F8>(xh, base0 + p * 8, e0, e1, f, iA, iB, a0, a1, a2, a3);
    for (int base = base0 + 32; base < e1; base += 32) {
      int my = base + p * 8;
      int4 jA = {0, 0, 0, 0}, jB = {0, 0, 0, 0};
      if (my < e1) jA = *(const int4*)(csrc + my);
      if (my + 4 < e1) jB = *(const int4*)(csrc + my + 4);
      rows8<F8>(xh, my, e0, e1, f, jA, jB, a0, a1, a2, a3);
    }

    // (4) reduce across the 4 p-groups (lane bits 4-5) + epilogue
    a0 += __shfl_xor(a0, 16); a0 += __shfl_xor(a0, 32);
    a1 += __shfl_xor(a1, 16); a1 += __shfl_xor(a1, 32);
    a2 += __shfl_xor(a2, 16); a2 += __shfl_xor(a2, 32);
    a3 += __shfl_xor(a3, 16); a3 += __shfl_xor(a3, 32);
    if (p == 0) {
      float sc = dinv[t] * invs;
      float4 bb = *(const float4*)(bias + f * 4);
      f16x4 hv;
      hv[0] = (_Float16)(fmaxf(a0 * sc + bb.x, 0.f) * 4096.f);
      hv[1] = (_Float16)(fmaxf(a1 * sc + bb.y, 0.f) * 4096.f);
      hv[2] = (_Float16)(fmaxf(a2 * sc + bb.z, 0.f) * 4096.f);
      hv[3] = (_Float16)(fmaxf(a3 * sc + bb.w, 0.f) * 4096.f);
      *(f16x4*)((char*)outp + ((size_t)(unsigned)t << 7) + f * 8) = hv;
    }

    // (5) rotate pipeline state
    if (tn >= n) break;
    t = tn; e0 = e0n; e1 = e1n; iA = iAn; iB = iBn;
    tn = tnn; e0n = e0nn; e1n = e1nn;
  }
}

// batch is sorted: per-wave register segment reduction over node-major fp16 y.
// lane = feature; per node one contiguous 128B row read.
__global__ __launch_bounds__(256) void k_pool(const _Float16* __restrict__ x,
                                              const int* __restrict__ batch,
                                              float* __restrict__ hsum,
                                              float* __restrict__ hmax,
                                              int* __restrict__ cntg,
                                              int n) {
  int wid = (blockIdx.x * blockDim.x + threadIdx.x) >> 6;
  int lane = threadIdx.x & 63;
  int i0 = wid * 64;
  if (i0 >= n) return;
  int i1 = min(i0 + 64, n);
  int batch_l = (i0 + lane < n) ? batch[i0 + lane] : 0;
  float gsum = 0.f, gmax = 0.f;
  int cur = __shfl(batch_l, 0);
  int c = 0;
  for (int i = i0; i < i1; i++) {
    int g = __shfl(batch_l, i - i0);
    if (g != cur) {
      atomicAdd(&hsum[cur * 64 + lane], gsum);
      atomicMax((int*)&hmax[cur * 64 + lane], __float_as_int(gmax));
      if (lane == 0) atomicAdd(&cntg[cur], c);
      gsum = 0.f; gmax = 0.f; c = 0; cur = g;
    }
    float v = (float)x[((size_t)(unsigned)i << 6) + lane];   // relu+bias folded, x4096
    gsum += v;
    gmax = fmaxf(gmax, v);
    c++;
  }
  atomicAdd(&hsum[cur * 64 + lane], gsum);
  atomicMax((int*)&hmax[cur * 64 + lane], __float_as_int(gmax));
  if (lane == 0) atomicAdd(&cntg[cur], c);
}

// one block (64 threads) per graph: logits = relu(h@Wc1+bc1)@Wc2+bc2
// hsum/hmax carry the 4096x scale; undone here.
__global__ __launch_bounds__(64) void k_cls(const float* __restrict__ hsum,
                                            const float* __restrict__ hmax,
                                            const int* __restrict__ cnt,
                                            const float* __restrict__ Wc1,
                                            const float* __restrict__ bc1,
                                            const float* __restrict__ Wc2,
                                            const float* __restrict__ bc2,
                                            float* __restrict__ out) {
  __shared__ float h[128];
  __shared__ float hid[64];
  int g = blockIdx.x, j = threadIdx.x;
  int c = cnt[g];
  float cf = (float)(c > 0 ? c : 1);
  h[j] = hsum[g * 64 + j] / cf * (1.0f / 4096.0f);
  h[64 + j] = hmax[g * 64 + j] * (1.0f / 4096.0f);
  __syncthreads();
  float acc = bc1[j];
  for (int k = 0; k < 128; k++) acc += h[k] * Wc1[k * 64 + j];
  hid[j] = fmaxf(acc, 0.f);
  __syncthreads();
  if (j < 2) {
    float a = bc2[j];
    for (int k = 0; k < 64; k++) a += hid[k] * Wc2[k * 2 + j];
    out[g * 2 + j] = a;
  }
}

extern "C" void kernel_launch(void* const* d_in, const int* in_sizes, int n_in,
                              void* d_out, int out_size, void* d_ws, size_t ws_size,
                              hipStream_t stream) {
  const int N = in_sizes[0];
  const int E = in_sizes[1] / 2;
  const int G = out_size / 2;
  const int B = (N + BKT - 1) >> BKT_LOG;
  const int Npad = (N + 63) & ~63;
  // padded bucket stride: 1.5x mean occupancy + 256, rounded to 8 so that
  // bucket bases stay 8-int aligned (int4 index loads in k_aggregate)
  const int S = ((((E + B - 1) / B) * 3 / 2 + 256) + 7) & ~7;

  const int* tok   = (const int*)d_in[0];
  const int* ei    = (const int*)d_in[1];
  const int* batch = (const int*)d_in[2];
  const float* emb = (const float*)d_in[3];
  const float* W0 = (const float*)d_in[4];  const float* b0 = (const float*)d_in[5];
  const float* W1 = (const float*)d_in[6];  const float* b1 = (const float*)d_in[7];
  const float* W2 = (const float*)d_in[8];  const float* b2 = (const float*)d_in[9];
  const float* Wc1 = (const float*)d_in[10]; const float* bc1 = (const float*)d_in[11];
  const float* Wc2 = (const float*)d_in[12]; const float* bc2 = (const float*)d_in[13];
  const int* srcp = ei;
  const int* dstp = ei + E;

  // ---- workspace carve-up (4-byte units) ----
  int* off    = (int*)d_ws;                      // N
  int* eend   = off + N;                         // N
  float* dinv = (float*)(eend + N);              // Npad
  int* gcur   = (int*)(dinv + Npad);             // 256
  _Float16* Wf = (_Float16*)(gcur + 256);        // 3*4096 halfs (24 KB)
  int* csrc   = (int*)(Wf + 3 * 4096);           // B*S (padded, ~9.8 MB)
  unsigned char* xh = (unsigned char*)(csrc + (size_t)B * S);  // Npad rows:
                                                 // fp8 64B (L0/L1) or fp16 128B (L2)
  _Float16* y  = (_Float16*)(xh + (size_t)Npad * 128);  // Npad x 64 fp16
  int* ebuf   = (int*)y;                         // B*S ints, aliases y (dead
                                                 // before first aggregate)
  float* hsum = (float*)(y + (size_t)Npad * 64); // G*64
  float* hmax = hsum + (size_t)G * 64;           // G*64
  int*   cntg = (int*)(hmax + (size_t)G * 64);   // G

  auto cdiv = [](long a, long b) { return (int)((a + b - 1) / b); };
  const int aggBlocks = 2048;                    // persistent: 8192 waves
  const int aggStride = aggBlocks * 4;

  // ---- weight conversion + workspace zeroing ----
  k_wcvt<<<5, 256, 0, stream>>>(W0, W1, W2, Wf, gcur, hsum, G * 129);

  // ---- CSR build (padded buckets; self-loops folded in) ----
  k_part<<<cdiv(E, CHUNK), 256, 0, stream>>>(srcp, dstp, gcur, ebuf, E, S);
  k_bplace<<<B, 512, 0, stream>>>(ebuf, gcur, off, eend, csrc, dinv, N, S);

  // ---- 3 GCN layers ----
  // L0 (fp8 rows): xh = fp8(emb@W0*dinv*256); agg invs=1/256.
  k_mfmamm<true, true><<<cdiv(N, 64), 256, 0, stream>>>(nullptr, tok, emb, Wf, dinv, 256.f, xh, N);
  k_aggregate<true><<<aggBlocks, 256, 0, stream>>>(off, eend, csrc, dinv, xh, b0, 1.f / 256.f, y, N, aggStride);

  // L1 (fp8 rows): y carries x4096; scale=1.0 -> fp8 normals; invs=1/4096.
  k_mfmamm<false, true><<<cdiv(N, 64), 256, 0, stream>>>(y, nullptr, nullptr, Wf + 4096, dinv, 1.0f, xh, N);
  k_aggregate<true><<<aggBlocks, 256, 0, stream>>>(off, eend, csrc, dinv, xh, b1, 1.f / 4096.f, y, N, aggStride);

  // L2 (fp16 rows, exact r21 numerics): scale=1/16, invs=1/256.
  k_mfmamm<false, false><<<cdiv(N, 64), 256, 0, stream>>>(y, nullptr, nullptr, Wf + 8192, dinv, 1.f / 16.f, xh, N);
  k_aggregate<false><<<aggBlocks, 256, 0, stream>>>(off, eend, csrc, dinv, xh, b2, 1.f / 256.f, y, N, aggStride);

  // ---- pooling ----
  k_pool<<<cdiv(N, 256), 256, 0, stream>>>(y, batch, hsum, hmax, cntg, N);

  // ---- classifier head ----
  k_cls<<<G, 64, 0, stream>>>(hsum, hmax, cntg, Wc1, bc1, Wc2, bc2, (float*)d_out);
}